// Round 2
// baseline (301.997 us; speedup 1.0000x reference)
//
#include <hip/hip_runtime.h>
#include <hip/hip_fp16.h>

// RiRoIAlign on gfx950 — round 7.
// Round-7 change (gather only): shuffle-free gather. Lane = binquad(4) x
// chgroup(16); each lane accumulates all 4 samples x 4 corners of ONE bin
// for its 8 channels (16x 16B loads, identical total bytes/coalescing as
// round 6). Removes all 16 __shfl_xor per bin (xor32 = ds_bpermute round
// trips) and the cn==0 divergent blend (was 16/64 lanes active). Critical
// path drops 7 bin-iters -> 2 passes. Descriptors re-laid out [bin][slot][cn]
// so one sample = one ds_read_b128 pair broadcast across the bin-group.
// Transpose kernel byte-identical to rounds 5/6 (control).

typedef _Float16 h16;
typedef _Float16 h8 __attribute__((ext_vector_type(8)));   // 16 B

#define NS 196          // 14*14 sample points per roi
#define HW 65536        // 256*256
#define TWO_PI_F 6.283185307179586f
#define OPITCH 132      // gather LDS out-tile pitch (128 ch + pad)
#define TP 40           // transpose LDS pitch in halves

// ------- transpose+cvt: feat[b][ch][px] f32 -> ft[b][px][ch] f16 -------
__global__ __launch_bounds__(256) void transpose_kernel(
    const float* __restrict__ in, h16* __restrict__ out)
{
    __shared__ h16 lds[256 * TP];     // [px 0..255][ch 0..31], pitch TP
    const int t = threadIdx.x;
    const int a = t & 63;             // pixel/4 index within tile
    const int w = t >> 6;             // wave: channel octet

    const int b  = blockIdx.z;
    const int tc = blockIdx.y;        // channel tile (32 ch)
    const int tp = blockIdx.x;        // pixel tile (256 px)

    const float* ip = in + ((size_t)b * 256 + tc * 32 + w * 8) * HW + tp * 256 + a * 4;

    float4 v[8];
    #pragma unroll
    for (int j = 0; j < 8; ++j)
        v[j] = *(const float4*)(ip + (size_t)j * HW);   // ch w*8+j, px 4a..4a+3

    #pragma unroll
    for (int p = 0; p < 4; ++p) {
        h8 row;
        #pragma unroll
        for (int j = 0; j < 8; ++j)
            row[j] = (h16)(((const float*)&v[j])[p]);
        *(h8*)&lds[(a * 4 + p) * TP + w * 8] = row;
    }
    __syncthreads();

    h16* op = out + ((size_t)b * HW + (size_t)tp * 256) * 256 + tc * 32;
    #pragma unroll
    for (int k = 0; k < 4; ++k) {
        int px   = (t >> 2) + k * 64;
        int part = t & 3;
        h8 r = *(const h8*)&lds[px * TP + part * 8];
        *(h8*)(op + (size_t)px * 256 + part * 8) = r;
    }
}

// ---------------- gather from fp16 NHWC, channel-split ----------------
__global__ __launch_bounds__(512, 8) void riroi_gather(
    const h16* __restrict__ ft, const float* __restrict__ rois,
    float* __restrict__ out)
{
    const int r    = blockIdx.x >> 1;
    const int half = blockIdx.x & 1;     // ch 0..127 or 128..255
    const int tid  = threadIdx.x;
    const int lane = tid & 63;
    const int wave = tid >> 6;           // 0..7
    const int bq   = lane >> 4;          // bin-quad slot 0..3
    const int chg  = lane & 15;          // channel group (8 ch each)

    const float* roi = rois + r * 6;
    int bb = (int)roi[0];
    const float cw = roi[1] * 0.125f;
    const float ch = roi[2] * 0.125f;
    const float rw = fmaxf(roi[3] * 0.125f, 1.0f);
    const float rh = fmaxf(roi[4] * 0.125f, 1.0f);
    const float theta = roi[5];

    const float ind_f = theta * 8.0f / TWO_PI_F;
    const float fl    = floorf(ind_f);
    const float lvar  = ind_f - fl;
    const float rvar  = 1.0f - lvar;
    int ii = (int)fl;
    int ind_v = ((ii % 8) + 8) & 7;
    // uniform per block -> force to SGPR, frees VGPRs under the 64-reg cap
    const int b   = __builtin_amdgcn_readfirstlane(bb);
    const int ind = __builtin_amdgcn_readfirstlane(ind_v);

    const float cost = cosf(theta), sint = sinf(theta);
    const float bin_h = rh * (1.0f / 7.0f), bin_w = rw * (1.0f / 7.0f);

    __shared__ int   s_off[49 * 16];     // [bin][slot][corner] elem offsets
    __shared__ float s_w  [49 * 16];
    __shared__ float s_out[49 * OPITCH]; // [bin][ch-half] plane-space

    if (tid < NS) {
        int iy = tid / 14, ix = tid - iy * 14;
        int py = iy >> 1, gy = iy & 1;
        int px = ix >> 1, gx = ix & 1;
        int bin  = py * 7 + px;
        int slot = (gy << 1) | gx;
        int base = (bin << 4) + (slot << 2);    // [bin][slot][0]
        float yy = ((float)py + ((float)gy + 0.5f) * 0.5f) * bin_h - rh * 0.5f;
        float xx = ((float)px + ((float)gx + 0.5f) * 0.5f) * bin_w - rw * 0.5f;
        float x = xx * cost - yy * sint + cw;
        float y = xx * sint + yy * cost + ch;
        float vm = (y > -1.0f && y < 256.0f && x > -1.0f && x < 256.0f) ? 1.0f : 0.0f;
        float yc = fmaxf(y, 0.0f), xc = fmaxf(x, 0.0f);
        int y0 = (int)yc, x0 = (int)xc;
        int y1, x1; float yv, xv;
        if (y0 >= 255) { y0 = 255; y1 = 255; yv = 255.0f; }
        else           { y1 = y0 + 1; yv = yc; }
        if (x0 >= 255) { x0 = 255; x1 = 255; xv = 255.0f; }
        else           { x1 = x0 + 1; xv = xc; }
        float ly = yv - (float)y0, lx = xv - (float)x0;
        float hy = 1.0f - ly, hx = 1.0f - lx;
        int y0w = y0 << 8, y1w = y1 << 8;
        *(int4*)&s_off[base] = make_int4((y0w + x0) << 8, (y0w + x1) << 8,
                                         (y1w + x0) << 8, (y1w + x1) << 8);
        *(float4*)&s_w[base] = make_float4(hy * hx * vm, hy * lx * vm,
                                           ly * hx * vm, ly * lx * vm);
    }
    __syncthreads();

    const h16* fb = ft + (size_t)b * ((size_t)HW * 256) + half * 128 + (chg << 3);

    #pragma unroll
    for (int pass = 0; pass < 2; ++pass) {
        const int bin = pass * 32 + (wave << 2) + bq;
        if (bin < 49) {
            const int dbase = bin << 4;
            float v[8] = {0.f, 0.f, 0.f, 0.f, 0.f, 0.f, 0.f, 0.f};
            #pragma unroll
            for (int s = 0; s < 4; ++s) {
                int4   o = *(const int4*)  &s_off[dbase + (s << 2)];
                float4 w = *(const float4*)&s_w  [dbase + (s << 2)];
                h8 f0 = *(const h8*)(fb + o.x);
                h8 f1 = *(const h8*)(fb + o.y);
                h8 f2 = *(const h8*)(fb + o.z);
                h8 f3 = *(const h8*)(fb + o.w);
                #pragma unroll
                for (int i = 0; i < 8; ++i)
                    v[i] += w.x * (float)f0[i] + w.y * (float)f1[i]
                          + w.z * (float)f2[i] + w.w * (float)f3[i];
            }
            // in-lane orientation blend: element i IS plane j=i
            float res[8];
            #pragma unroll
            for (int i = 0; i < 8; ++i)
                res[i] = 0.25f * (rvar * v[i] + lvar * v[(i + 1) & 7]);
            float* dst = &s_out[bin * OPITCH + (chg << 3)];
            *(float4*)dst       = make_float4(res[0], res[1], res[2], res[3]);
            *(float4*)(dst + 4) = make_float4(res[4], res[5], res[6], res[7]);
        }
    }
    __syncthreads();

    // coalesced writeback with orientation permutation (octet-local)
    const int ind_neg = (8 - ind) & 7;
    float* ob = out + (size_t)r * 12544 + half * 6272;
    for (int i = tid << 2; i < 6272; i += 2048) {
        float4 vo;
        #pragma unroll
        for (int q = 0; q < 4; ++q) {
            int j   = i + q;
            int co  = j / 49;            // local channel 0..127
            int bin = j - co * 49;
            int ci  = (co & ~7) | ((co + ind_neg) & 7);
            ((float*)&vo)[q] = s_out[bin * OPITCH + ci];
        }
        *(float4*)(ob + i) = vo;
    }
}

extern "C" void kernel_launch(void* const* d_in, const int* in_sizes, int n_in,
                              void* d_out, int out_size, void* d_ws, size_t ws_size,
                              hipStream_t stream) {
    const float* feat = (const float*)d_in[0];   // 2*256*256*256 f32
    const float* rois = (const float*)d_in[1];   // 512*6 f32
    float* out = (float*)d_out;                  // 512*256*7*7 f32

    h16* ft = (h16*)d_ws;                        // 2*65536*256 f16 = 67 MB
    transpose_kernel<<<dim3(256, 8, 2), dim3(256), 0, stream>>>(feat, ft);
    riroi_gather<<<dim3(1024), dim3(512), 0, stream>>>(ft, rois, out);
}

// Round 3
// 240.839 us; speedup vs baseline: 1.2539x; 1.2539x over previous
//
#include <hip/hip_runtime.h>
#include <hip/hip_fp16.h>

// RiRoIAlign on gfx950 — round 8.
// Revert gather to round-6 structure (round-7 bin-parallel mapping was a
// -59us regression: lost per-instruction bilinear-footprint locality,
// 1.33M LDS conflicts). Two micro-fixes on top:
//  - gather: xor32 corner-fold via v_permlane32_swap_b32 (VALU) instead of
//    __shfl_xor(32) (= ds_bpermute round-trip). r0+r1 gives the fold in all
//    lanes. 8 fewer DS ops per bin.
//  - transpose: LDS write phase was a 4x bank conflict (lane stride 320B ->
//    2 bank-quads). XOR col-block swizzle: write w^(a&3), read part^((px>>2)&3).
//    Write conflict 4x->2x, read stays at 8-cycle minimum.

typedef _Float16 h16;
typedef _Float16 h8 __attribute__((ext_vector_type(8)));   // 16 B

#define NS 196          // 14*14 sample points per roi
#define HW 65536        // 256*256
#define TWO_PI_F 6.283185307179586f
#define OPITCH 132      // gather LDS out-tile pitch (128 ch + pad)
#define TP 40           // transpose LDS pitch in halves

// ------- transpose+cvt: feat[b][ch][px] f32 -> ft[b][px][ch] f16 -------
__global__ __launch_bounds__(256) void transpose_kernel(
    const float* __restrict__ in, h16* __restrict__ out)
{
    __shared__ h16 lds[256 * TP];     // [px 0..255][ch 0..31], pitch TP
    const int t = threadIdx.x;
    const int a = t & 63;             // pixel/4 index within tile
    const int w = t >> 6;             // wave: channel octet

    const int b  = blockIdx.z;
    const int tc = blockIdx.y;        // channel tile (32 ch)
    const int tp = blockIdx.x;        // pixel tile (256 px)

    const float* ip = in + ((size_t)b * 256 + tc * 32 + w * 8) * HW + tp * 256 + a * 4;

    float4 v[8];
    #pragma unroll
    for (int j = 0; j < 8; ++j)
        v[j] = *(const float4*)(ip + (size_t)j * HW);   // ch w*8+j, px 4a..4a+3

    const int wsw = (w ^ (a & 3)) * 8;   // XOR col-block swizzle (write side)
    #pragma unroll
    for (int p = 0; p < 4; ++p) {
        h8 row;
        #pragma unroll
        for (int j = 0; j < 8; ++j)
            row[j] = (h16)(((const float*)&v[j])[p]);
        *(h8*)&lds[(a * 4 + p) * TP + wsw] = row;
    }
    __syncthreads();

    h16* op = out + ((size_t)b * HW + (size_t)tp * 256) * 256 + tc * 32;
    #pragma unroll
    for (int k = 0; k < 4; ++k) {
        int px   = (t >> 2) + k * 64;
        int part = t & 3;
        int pps  = (part ^ ((px >> 2) & 3)) * 8;   // un-swizzle on read
        h8 r = *(const h8*)&lds[px * TP + pps];
        *(h8*)(op + (size_t)px * 256 + part * 8) = r;
    }
}

// ---------------- gather from fp16 NHWC, channel-split ----------------
__global__ __launch_bounds__(512, 8) void riroi_gather(
    const h16* __restrict__ ft, const float* __restrict__ rois,
    float* __restrict__ out)
{
    const int r    = blockIdx.x >> 1;
    const int half = blockIdx.x & 1;     // ch 0..127 or 128..255
    const int tid  = threadIdx.x;
    const int lane = tid & 63;
    const int wave = tid >> 6;           // 0..7
    const int cn   = lane >> 4;          // bilinear corner 0..3
    const int chg  = lane & 15;          // channel group (8 ch each)

    const float* roi = rois + r * 6;
    int bb = (int)roi[0];
    const float cw = roi[1] * 0.125f;
    const float ch = roi[2] * 0.125f;
    const float rw = fmaxf(roi[3] * 0.125f, 1.0f);
    const float rh = fmaxf(roi[4] * 0.125f, 1.0f);
    const float theta = roi[5];

    const float ind_f = theta * 8.0f / TWO_PI_F;
    const float fl    = floorf(ind_f);
    const float lvar  = ind_f - fl;
    const float rvar  = 1.0f - lvar;
    int ii = (int)fl;
    int ind_v = ((ii % 8) + 8) & 7;
    // uniform per block -> force to SGPR, frees VGPRs under the 64-reg cap
    const int b   = __builtin_amdgcn_readfirstlane(bb);
    const int ind = __builtin_amdgcn_readfirstlane(ind_v);

    const float cost = cosf(theta), sint = sinf(theta);
    const float bin_h = rh * (1.0f / 7.0f), bin_w = rw * (1.0f / 7.0f);

    __shared__ int   s_off[4][49 * 4];   // [corner][bin*4 + slot], elem offset
    __shared__ float s_w[4][49 * 4];
    __shared__ float s_out[49 * OPITCH]; // [bin][ch-half] plane-space

    if (tid < NS) {
        int iy = tid / 14, ix = tid - iy * 14;
        int py = iy >> 1, gy = iy & 1;
        int px = ix >> 1, gx = ix & 1;
        int q = (py * 7 + px) * 4 + ((gy << 1) | gx);   // bin*4 + slot
        float yy = ((float)py + ((float)gy + 0.5f) * 0.5f) * bin_h - rh * 0.5f;
        float xx = ((float)px + ((float)gx + 0.5f) * 0.5f) * bin_w - rw * 0.5f;
        float x = xx * cost - yy * sint + cw;
        float y = xx * sint + yy * cost + ch;
        float vm = (y > -1.0f && y < 256.0f && x > -1.0f && x < 256.0f) ? 1.0f : 0.0f;
        float yc = fmaxf(y, 0.0f), xc = fmaxf(x, 0.0f);
        int y0 = (int)yc, x0 = (int)xc;
        int y1, x1; float yv, xv;
        if (y0 >= 255) { y0 = 255; y1 = 255; yv = 255.0f; }
        else           { y1 = y0 + 1; yv = yc; }
        if (x0 >= 255) { x0 = 255; x1 = 255; xv = 255.0f; }
        else           { x1 = x0 + 1; xv = xc; }
        float ly = yv - (float)y0, lx = xv - (float)x0;
        float hy = 1.0f - ly, hx = 1.0f - lx;
        s_w[0][q] = hy * hx * vm;
        s_w[1][q] = hy * lx * vm;
        s_w[2][q] = ly * hx * vm;
        s_w[3][q] = ly * lx * vm;
        int y0w = y0 << 8, y1w = y1 << 8;
        s_off[0][q] = (y0w + x0) << 8;   // pre-scaled by 256 channels
        s_off[1][q] = (y0w + x1) << 8;
        s_off[2][q] = (y1w + x0) << 8;
        s_off[3][q] = (y1w + x1) << 8;
    }
    __syncthreads();

    const h16* fb = ft + (size_t)b * ((size_t)HW * 256) + half * 128 + (chg << 3);

    int myb = wave;
    int4   off = *(const int4*)  &s_off[cn][myb << 2];
    float4 wv  = *(const float4*)&s_w  [cn][myb << 2];
    while (myb < 49) {
        // 4 independent 16B loads, addresses already in registers
        h8 f0 = *(const h8*)(fb + off.x);
        h8 f1 = *(const h8*)(fb + off.y);
        h8 f2 = *(const h8*)(fb + off.z);
        h8 f3 = *(const h8*)(fb + off.w);

        // prefetch next bin's descriptors (branchless clamp keeps read valid)
        int nb = myb + 8;
        int pb = (nb < 49) ? nb : myb;
        int4   off_n = *(const int4*)  &s_off[cn][pb << 2];
        float4 wv_n  = *(const float4*)&s_w  [cn][pb << 2];

        float v[8];
        #pragma unroll
        for (int i = 0; i < 8; ++i)
            v[i] = wv.x * (float)f0[i] + wv.y * (float)f1[i]
                 + wv.z * (float)f2[i] + wv.w * (float)f3[i];

        // fold the 4 corner groups: xor16 via shuffle, xor32 via permlane
        #pragma unroll
        for (int i = 0; i < 8; ++i) {
            v[i] += __shfl_xor(v[i], 16);
            unsigned u = __float_as_uint(v[i]);
            auto pr = __builtin_amdgcn_permlane32_swap(u, u, false, false);
            v[i] = __uint_as_float(pr[0]) + __uint_as_float(pr[1]);
        }
        if (cn == 0) {
            // in-lane orientation blend: element i IS plane j=i
            float res[8];
            #pragma unroll
            for (int i = 0; i < 8; ++i)
                res[i] = 0.25f * (rvar * v[i] + lvar * v[(i + 1) & 7]);
            float* dst = &s_out[myb * OPITCH + (chg << 3)];
            *(float4*)dst       = make_float4(res[0], res[1], res[2], res[3]);
            *(float4*)(dst + 4) = make_float4(res[4], res[5], res[6], res[7]);
        }
        myb = nb; off = off_n; wv = wv_n;
    }
    __syncthreads();

    // coalesced writeback with orientation permutation (octet-local)
    const int ind_neg = (8 - ind) & 7;
    float* ob = out + (size_t)r * 12544 + half * 6272;
    for (int i = tid << 2; i < 6272; i += 2048) {
        float4 vo;
        #pragma unroll
        for (int q = 0; q < 4; ++q) {
            int j   = i + q;
            int co  = j / 49;            // local channel 0..127
            int bin = j - co * 49;
            int ci  = (co & ~7) | ((co + ind_neg) & 7);
            ((float*)&vo)[q] = s_out[bin * OPITCH + ci];
        }
        *(float4*)(ob + i) = vo;
    }
}

extern "C" void kernel_launch(void* const* d_in, const int* in_sizes, int n_in,
                              void* d_out, int out_size, void* d_ws, size_t ws_size,
                              hipStream_t stream) {
    const float* feat = (const float*)d_in[0];   // 2*256*256*256 f32
    const float* rois = (const float*)d_in[1];   // 512*6 f32
    float* out = (float*)d_out;                  // 512*256*7*7 f32

    h16* ft = (h16*)d_ws;                        // 2*65536*256 f16 = 67 MB
    transpose_kernel<<<dim3(256, 8, 2), dim3(256), 0, stream>>>(feat, ft);
    riroi_gather<<<dim3(1024), dim3(512), 0, stream>>>(ft, rois, out);
}

// Round 4
// 237.571 us; speedup vs baseline: 1.2712x; 1.0138x over previous
//
#include <hip/hip_runtime.h>
#include <hip/hip_fp16.h>

// RiRoIAlign on gfx950 — round 9.
// Round-8 structure kept (gather = round-6 + permlane xor32 fold; transpose
// swizzled). New: XCD-locality roi scheduling. Rois are bucketed by spatial
// tile (4 y-bands x 2 x-halves; one bucket's ft slice ~4.2MB ~ one XCD L2).
// Transpose block (0,0,0) counting-sorts the 1024 roi-halves by
// (bucket,half) into perm[] in ws (hidden under the other 4095 blocks).
// Gather block g takes sorted position (g&7)*128 + (g>>3), so XCD k
// (blocks == k mod 8, round-robin) stays inside bucket k's slice ->
// cross-roi L2 reuse (rois oversample the image ~9.6x; ideal unique
// traffic ~34MB vs the 157MB L2-miss fetch measured in round 7).
// Permutation is output-invariant: addressing follows roi id, not block id.

typedef _Float16 h16;
typedef _Float16 h8 __attribute__((ext_vector_type(8)));   // 16 B

#define NS 196          // 14*14 sample points per roi
#define HW 65536        // 256*256
#define TWO_PI_F 6.283185307179586f
#define OPITCH 132      // gather LDS out-tile pitch (128 ch + pad)
#define TP 40           // transpose LDS pitch in halves
#define FT_BYTES 67108864u   // 2*65536*256 * 2B

// ------- transpose+cvt: feat[b][ch][px] f32 -> ft[b][px][ch] f16 -------
__global__ __launch_bounds__(256) void transpose_kernel(
    const float* __restrict__ in, h16* __restrict__ out,
    const float* __restrict__ rois, int* __restrict__ perm)
{
    __shared__ h16 lds[256 * TP];     // [px 0..255][ch 0..31], pitch TP
    const int t = threadIdx.x;
    const int a = t & 63;             // pixel/4 index within tile
    const int w = t >> 6;             // wave: channel octet

    const int b  = blockIdx.z;
    const int tc = blockIdx.y;        // channel tile (32 ch)
    const int tp = blockIdx.x;        // pixel tile (256 px)

    const float* ip = in + ((size_t)b * 256 + tc * 32 + w * 8) * HW + tp * 256 + a * 4;

    float4 v[8];
    #pragma unroll
    for (int j = 0; j < 8; ++j)
        v[j] = *(const float4*)(ip + (size_t)j * HW);   // ch w*8+j, px 4a..4a+3

    const int wsw = (w ^ (a & 3)) * 8;   // XOR col-block swizzle (write side)
    #pragma unroll
    for (int p = 0; p < 4; ++p) {
        h8 row;
        #pragma unroll
        for (int j = 0; j < 8; ++j)
            row[j] = (h16)(((const float*)&v[j])[p]);
        *(h8*)&lds[(a * 4 + p) * TP + wsw] = row;
    }
    __syncthreads();

    h16* op = out + ((size_t)b * HW + (size_t)tp * 256) * 256 + tc * 32;
    #pragma unroll
    for (int k = 0; k < 4; ++k) {
        int px   = (t >> 2) + k * 64;
        int part = t & 3;
        int pps  = (part ^ ((px >> 2) & 3)) * 4;   // un-swizzle on read (halves*? see below)
        // NOTE: pps must be in halves: part block is 8 halves wide
        h8 r = *(const h8*)&lds[px * TP + ((part ^ ((px >> 2) & 3)) * 8)];
        *(h8*)(op + (size_t)px * 256 + part * 8) = r;
        (void)pps;
    }

    // ---- roi-half -> block permutation (one block; hidden under the rest) ----
    if (blockIdx.x == 0 && blockIdx.y == 0 && blockIdx.z == 0) {
        __syncthreads();                       // lds reads above are done
        int* cnt  = (int*)&lds[0];             // 16 ints
        int* base = (int*)&lds[32];            // 16 ints
        if (t < 16) cnt[t] = 0;
        __syncthreads();
        int mykey[4], myrank[4];
        #pragma unroll
        for (int e = 0; e < 4; ++e) {
            int rh = t * 4 + e;                // 1024 roi-halves
            int r  = rh >> 1, h = rh & 1;
            float cx = rois[r * 6 + 1] * 0.125f;
            float cy = rois[r * 6 + 2] * 0.125f;
            int by = (int)cy >> 6;  by = by > 3 ? 3 : (by < 0 ? 0 : by);
            int bx = ((int)cx >> 7) & 1;
            int key = ((((by << 1) | bx) << 1) | h);   // (bucket,half) 0..15
            mykey[e]  = key;
            myrank[e] = atomicAdd(&cnt[key], 1);
        }
        __syncthreads();
        if (t == 0) {
            int s = 0;
            for (int k2 = 0; k2 < 16; ++k2) { base[k2] = s; s += cnt[k2]; }
        }
        __syncthreads();
        #pragma unroll
        for (int e = 0; e < 4; ++e)
            perm[base[mykey[e]] + myrank[e]] = t * 4 + e;
    }
}

// ---------------- gather from fp16 NHWC, channel-split ----------------
__global__ __launch_bounds__(512, 8) void riroi_gather(
    const h16* __restrict__ ft, const float* __restrict__ rois,
    float* __restrict__ out, const int* __restrict__ perm)
{
    const int g    = blockIdx.x;
    // XCD k (blocks == k mod 8) walks sorted positions k*128..k*128+127
    const int pos  = ((g & 7) << 7) + (g >> 3);
    const int rh_i = perm[pos];
    const int r    = rh_i >> 1;
    const int half = rh_i & 1;           // ch 0..127 or 128..255
    const int tid  = threadIdx.x;
    const int lane = tid & 63;
    const int wave = tid >> 6;           // 0..7
    const int cn   = lane >> 4;          // bilinear corner 0..3
    const int chg  = lane & 15;          // channel group (8 ch each)

    const float* roi = rois + r * 6;
    int bb = (int)roi[0];
    const float cw = roi[1] * 0.125f;
    const float ch = roi[2] * 0.125f;
    const float rw = fmaxf(roi[3] * 0.125f, 1.0f);
    const float rh = fmaxf(roi[4] * 0.125f, 1.0f);
    const float theta = roi[5];

    const float ind_f = theta * 8.0f / TWO_PI_F;
    const float fl    = floorf(ind_f);
    const float lvar  = ind_f - fl;
    const float rvar  = 1.0f - lvar;
    int ii = (int)fl;
    int ind_v = ((ii % 8) + 8) & 7;
    // uniform per block -> force to SGPR, frees VGPRs under the 64-reg cap
    const int b   = __builtin_amdgcn_readfirstlane(bb);
    const int ind = __builtin_amdgcn_readfirstlane(ind_v);

    const float cost = cosf(theta), sint = sinf(theta);
    const float bin_h = rh * (1.0f / 7.0f), bin_w = rw * (1.0f / 7.0f);

    __shared__ int   s_off[4][49 * 4];   // [corner][bin*4 + slot], elem offset
    __shared__ float s_w[4][49 * 4];
    __shared__ float s_out[49 * OPITCH]; // [bin][ch-half] plane-space

    if (tid < NS) {
        int iy = tid / 14, ix = tid - iy * 14;
        int py = iy >> 1, gy = iy & 1;
        int px = ix >> 1, gx = ix & 1;
        int q = (py * 7 + px) * 4 + ((gy << 1) | gx);   // bin*4 + slot
        float yy = ((float)py + ((float)gy + 0.5f) * 0.5f) * bin_h - rh * 0.5f;
        float xx = ((float)px + ((float)gx + 0.5f) * 0.5f) * bin_w - rw * 0.5f;
        float x = xx * cost - yy * sint + cw;
        float y = xx * sint + yy * cost + ch;
        float vm = (y > -1.0f && y < 256.0f && x > -1.0f && x < 256.0f) ? 1.0f : 0.0f;
        float yc = fmaxf(y, 0.0f), xc = fmaxf(x, 0.0f);
        int y0 = (int)yc, x0 = (int)xc;
        int y1, x1; float yv, xv;
        if (y0 >= 255) { y0 = 255; y1 = 255; yv = 255.0f; }
        else           { y1 = y0 + 1; yv = yc; }
        if (x0 >= 255) { x0 = 255; x1 = 255; xv = 255.0f; }
        else           { x1 = x0 + 1; xv = xc; }
        float ly = yv - (float)y0, lx = xv - (float)x0;
        float hy = 1.0f - ly, hx = 1.0f - lx;
        s_w[0][q] = hy * hx * vm;
        s_w[1][q] = hy * lx * vm;
        s_w[2][q] = ly * hx * vm;
        s_w[3][q] = ly * lx * vm;
        int y0w = y0 << 8, y1w = y1 << 8;
        s_off[0][q] = (y0w + x0) << 8;   // pre-scaled by 256 channels
        s_off[1][q] = (y0w + x1) << 8;
        s_off[2][q] = (y1w + x0) << 8;
        s_off[3][q] = (y1w + x1) << 8;
    }
    __syncthreads();

    const h16* fb = ft + (size_t)b * ((size_t)HW * 256) + half * 128 + (chg << 3);

    int myb = wave;
    int4   off = *(const int4*)  &s_off[cn][myb << 2];
    float4 wv  = *(const float4*)&s_w  [cn][myb << 2];
    while (myb < 49) {
        // 4 independent 16B loads, addresses already in registers
        h8 f0 = *(const h8*)(fb + off.x);
        h8 f1 = *(const h8*)(fb + off.y);
        h8 f2 = *(const h8*)(fb + off.z);
        h8 f3 = *(const h8*)(fb + off.w);

        // prefetch next bin's descriptors (branchless clamp keeps read valid)
        int nb = myb + 8;
        int pb = (nb < 49) ? nb : myb;
        int4   off_n = *(const int4*)  &s_off[cn][pb << 2];
        float4 wv_n  = *(const float4*)&s_w  [cn][pb << 2];

        float v[8];
        #pragma unroll
        for (int i = 0; i < 8; ++i)
            v[i] = wv.x * (float)f0[i] + wv.y * (float)f1[i]
                 + wv.z * (float)f2[i] + wv.w * (float)f3[i];

        // fold the 4 corner groups: xor16 via shuffle, xor32 via permlane
        #pragma unroll
        for (int i = 0; i < 8; ++i) {
            v[i] += __shfl_xor(v[i], 16);
            unsigned u = __float_as_uint(v[i]);
            auto pr = __builtin_amdgcn_permlane32_swap(u, u, false, false);
            v[i] = __uint_as_float(pr[0]) + __uint_as_float(pr[1]);
        }
        if (cn == 0) {
            // in-lane orientation blend: element i IS plane j=i
            float res[8];
            #pragma unroll
            for (int i = 0; i < 8; ++i)
                res[i] = 0.25f * (rvar * v[i] + lvar * v[(i + 1) & 7]);
            float* dst = &s_out[myb * OPITCH + (chg << 3)];
            *(float4*)dst       = make_float4(res[0], res[1], res[2], res[3]);
            *(float4*)(dst + 4) = make_float4(res[4], res[5], res[6], res[7]);
        }
        myb = nb; off = off_n; wv = wv_n;
    }
    __syncthreads();

    // coalesced writeback with orientation permutation (octet-local)
    const int ind_neg = (8 - ind) & 7;
    float* ob = out + (size_t)r * 12544 + half * 6272;
    for (int i = tid << 2; i < 6272; i += 2048) {
        float4 vo;
        #pragma unroll
        for (int q = 0; q < 4; ++q) {
            int j   = i + q;
            int co  = j / 49;            // local channel 0..127
            int bin = j - co * 49;
            int ci  = (co & ~7) | ((co + ind_neg) & 7);
            ((float*)&vo)[q] = s_out[bin * OPITCH + ci];
        }
        *(float4*)(ob + i) = vo;
    }
}

extern "C" void kernel_launch(void* const* d_in, const int* in_sizes, int n_in,
                              void* d_out, int out_size, void* d_ws, size_t ws_size,
                              hipStream_t stream) {
    const float* feat = (const float*)d_in[0];   // 2*256*256*256 f32
    const float* rois = (const float*)d_in[1];   // 512*6 f32
    float* out = (float*)d_out;                  // 512*256*7*7 f32

    h16* ft   = (h16*)d_ws;                      // 2*65536*256 f16 = 64 MiB
    int* perm = (int*)((char*)d_ws + FT_BYTES);  // 1024 ints

    transpose_kernel<<<dim3(256, 8, 2), dim3(256), 0, stream>>>(feat, ft, rois, perm);
    riroi_gather<<<dim3(1024), dim3(512), 0, stream>>>(ft, rois, out, perm);
}